// Round 2
// baseline (137.824 us; speedup 1.0000x reference)
//
#include <hip/hip_runtime.h>

// Problem constants (B=1 fixed by reference)
#define HW_TOTAL (480 * 640)          // 307200 pixels
#define NC 12                          // output channels (C-1)
#define VOX_TOTAL_C (240 * 144 * 240)  // 8,294,400 voxels (divisible by 4)

// Phase 1: scatter pixel index into inverse map. inv[] pre-zeroed; store p+1
// so 0 means "no pixel maps here". Map values are unique (permutation) ->
// no write conflicts.
__global__ void build_inv_kernel(const int* __restrict__ map,
                                 int* __restrict__ inv) {
    int p = blockIdx.x * blockDim.x + threadIdx.x;
    if (p >= HW_TOTAL) return;
    int v = map[p];
    if (v > 0) inv[v] = p + 1;   // v==0 means invalid pixel (dropped)
}

// Phase 2: sequential gather over voxels, 4 voxels/thread via int4/float4.
// out write is fully-coalesced streaming (full cache lines -> no write-
// allocate fetch). x is 16 MB -> L2/L3 resident for the scattered reads.
__global__ void gather_kernel(const float* __restrict__ x,
                              const int* __restrict__ inv,
                              float* __restrict__ out) {
    int t = blockIdx.x * blockDim.x + threadIdx.x;
    if (t >= VOX_TOTAL_C / 4) return;
    int4 pv = ((const int4*)inv)[t];
    size_t base = (size_t)t * 4;
    bool any = (pv.x | pv.y | pv.z | pv.w) != 0;  // entries are p+1 (>0) or 0
#pragma unroll
    for (int c = 0; c < NC; ++c) {
        float4 o = make_float4(0.f, 0.f, 0.f, 0.f);
        if (any) {
            const float* xc = x + (size_t)(c + 1) * HW_TOTAL;
            if (pv.x > 0) o.x = xc[pv.x - 1];
            if (pv.y > 0) o.y = xc[pv.y - 1];
            if (pv.z > 0) o.z = xc[pv.z - 1];
            if (pv.w > 0) o.w = xc[pv.w - 1];
        }
        *(float4*)(out + (size_t)c * VOX_TOTAL_C + base) = o;
    }
}

extern "C" void kernel_launch(void* const* d_in, const int* in_sizes, int n_in,
                              void* d_out, int out_size, void* d_ws, size_t ws_size,
                              hipStream_t stream) {
    const float* x = (const float*)d_in[0];      // (1, 13, 480, 640) f32
    const int* map = (const int*)d_in[1];        // (1, 307200) i32
    float* out = (float*)d_out;                  // (1, 12, 240, 144, 240) f32
    int* inv = (int*)d_ws;                       // VOX_TOTAL_C ints = 33.2 MB

    const size_t inv_bytes = (size_t)VOX_TOTAL_C * sizeof(int);

    if (ws_size < inv_bytes) {
        // Fallback: shouldn't happen, but keep a correct path.
        hipMemsetAsync(out, 0, (size_t)NC * VOX_TOTAL_C * sizeof(float), stream);
        return;  // (would be wrong, but ws is always large enough in harness)
    }

    // Zero the inverse map every call (harness poisons d_ws with 0xAA).
    hipMemsetAsync(inv, 0, inv_bytes, stream);

    {
        const int threads = 256;
        const int blocks = (HW_TOTAL + threads - 1) / threads;
        build_inv_kernel<<<blocks, threads, 0, stream>>>(map, inv);
    }
    {
        const int threads = 256;
        const int total = VOX_TOTAL_C / 4;                // 2,073,600
        const int blocks = (total + threads - 1) / threads; // 8100
        gather_kernel<<<blocks, threads, 0, stream>>>(x, inv, out);
    }
}

// Round 3
// 113.593 us; speedup vs baseline: 1.2133x; 1.2133x over previous
//
#include <hip/hip_runtime.h>

// Problem constants (B=1 fixed by reference)
#define HW_TOTAL (480 * 640)           // 307200 pixels
#define NC 12                           // output channels (C-1)
#define VOX_TOTAL_C (240 * 144 * 240)   // 8,294,400 voxels (divisible by 4)

typedef float f32x4 __attribute__((ext_vector_type(4)));
typedef int   i32x4 __attribute__((ext_vector_type(4)));

// k1: transpose x (13, HW) -> xT (HW, 12), keeping channels 1..12.
// LDS-staged so both the global reads and writes are fully coalesced.
__global__ void transpose_kernel(const float* __restrict__ x,
                                 float* __restrict__ xT) {
    __shared__ float lds[256 * 13];   // pad 12->13 to break bank conflicts
    const int tid = threadIdx.x;
    const int p0 = blockIdx.x * 256;
#pragma unroll
    for (int c = 0; c < NC; ++c)
        lds[tid * 13 + c] = x[(size_t)(c + 1) * HW_TOTAL + p0 + tid];
    __syncthreads();
    float* dst = xT + (size_t)p0 * NC;
#pragma unroll
    for (int it = 0; it < NC; ++it) {
        int j = it * 256 + tid;
        dst[j] = lds[(j / NC) * 13 + (j % NC)];
    }
}

// k2: scatter pixel index into inverse map (inv pre-zeroed; p+1, 0 = empty).
// Map values are a permutation -> no conflicts.
__global__ void build_inv_kernel(const int* __restrict__ map,
                                 int* __restrict__ inv) {
    int p = blockIdx.x * blockDim.x + threadIdx.x;
    if (p >= HW_TOTAL) return;
    int v = map[p];
    if (v > 0) inv[v] = p + 1;   // v==0 means invalid pixel (dropped)
}

// k3: streaming gather. 4 voxels/thread. Valid voxels read one contiguous
// 48-B record from xT (3x float4) instead of 12 scattered 4-B loads.
// inv read + out write are nontemporal to keep L2 for xT.
__global__ void gather_kernel(const float* __restrict__ xT,
                              const int* __restrict__ inv,
                              float* __restrict__ out) {
    int t = blockIdx.x * blockDim.x + threadIdx.x;
    if (t >= VOX_TOTAL_C / 4) return;
    i32x4 pv = __builtin_nontemporal_load((const i32x4*)inv + t);
    float v[4][NC];
#pragma unroll
    for (int k = 0; k < 4; ++k) {
        int p = pv[k];
        if (p > 0) {
            const f32x4* r = (const f32x4*)(xT + (size_t)(p - 1) * NC);
            f32x4 a = r[0], b = r[1], c = r[2];
            v[k][0] = a.x; v[k][1] = a.y; v[k][2]  = a.z; v[k][3]  = a.w;
            v[k][4] = b.x; v[k][5] = b.y; v[k][6]  = b.z; v[k][7]  = b.w;
            v[k][8] = c.x; v[k][9] = c.y; v[k][10] = c.z; v[k][11] = c.w;
        } else {
#pragma unroll
            for (int c2 = 0; c2 < NC; ++c2) v[k][c2] = 0.f;
        }
    }
    size_t base = (size_t)t * 4;
#pragma unroll
    for (int c2 = 0; c2 < NC; ++c2) {
        f32x4 o = { v[0][c2], v[1][c2], v[2][c2], v[3][c2] };
        __builtin_nontemporal_store(o, (f32x4*)(out + (size_t)c2 * VOX_TOTAL_C + base));
    }
}

extern "C" void kernel_launch(void* const* d_in, const int* in_sizes, int n_in,
                              void* d_out, int out_size, void* d_ws, size_t ws_size,
                              hipStream_t stream) {
    const float* x = (const float*)d_in[0];      // (1, 13, 480, 640) f32
    const int* map = (const int*)d_in[1];        // (1, 307200) i32
    float* out = (float*)d_out;                  // (1, 12, 240, 144, 240) f32

    int*   inv = (int*)d_ws;                            // 33.2 MB
    float* xT  = (float*)((char*)d_ws +
                          (size_t)VOX_TOTAL_C * sizeof(int));  // 14.7 MB

    // Zero the inverse map every call (harness poisons d_ws with 0xAA).
    hipMemsetAsync(inv, 0, (size_t)VOX_TOTAL_C * sizeof(int), stream);

    {   // transpose: 1200 blocks x 256
        transpose_kernel<<<HW_TOTAL / 256, 256, 0, stream>>>(x, xT);
    }
    {   // build inverse map
        build_inv_kernel<<<HW_TOTAL / 256, 256, 0, stream>>>(map, inv);
    }
    {   // gather: 2,073,600 threads
        const int total = VOX_TOTAL_C / 4;
        gather_kernel<<<(total + 255) / 256, 256, 0, stream>>>(xT, inv, out);
    }
}